// Round 8
// baseline (319.383 us; speedup 1.0000x reference)
//
#include <hip/hip_runtime.h>

// ---------------------------------------------------------------------------
// 2-layer GCN, R8 = R7 + column-sliced aggregation.
// R7 post-mortem: aggs are LLC-rate-bound (~5.8 TB/s on a 12.8 MB table ->
// ~35 us each). Slice the feature dim into 4 passes of 32 halfs (64 B): each
// pass's gather slice is 3.2 MB -> resident in every XCD's 4 MiB L2, so
// gathers are served at L2 rate (~34 TB/s agg) after warm-up. Pass-major
// block ordering gives temporal separation; csr is re-read per pass via
// nontemporal loads so it doesn't evict the slice.
//   build: fixed-capacity buckets (scatter reserves ranges, one atomic per
//          (block,bucket)), rowstart/rowend per node, xs=fp16(x*dinv) fused.
//   q1 = fp16(dinv*(xs_self + sum xs[u]))   [agg128_sliced, 4 passes]
//   p2 = fp16(relu(q1@W1+b1)*dinv)          [MFMA gemm, fused epilogue]
//   q2 = fp16(dinv*(p2_self + sum p2[u]))   [agg128_sliced]
//   out = relu(q2@W2+b2) fp32               [MFMA gemm]
// ---------------------------------------------------------------------------

typedef __attribute__((ext_vector_type(8))) _Float16 half8;
typedef __attribute__((ext_vector_type(4))) _Float16 half4v;
typedef __attribute__((ext_vector_type(4))) float floatx4;

#define BSHIFT 7
#define BNODES 128       // nodes per bucket
#define BCAP   4096      // edge capacity per bucket (mean 2046, sigma ~45)

// ---- scatter packed (src | dst_low7<<16) into fixed bucket windows ---------
// Blocks [0,256): scatter. Blocks [256,448): W1/W2 fp32 -> fp16 transposed.
__global__ __launch_bounds__(256) void scatter_conv_kernel(const int* __restrict__ src,
                                                           const int* __restrict__ dst,
                                                           int* __restrict__ bucket_fill,
                                                           unsigned* __restrict__ bucketed,
                                                           const float* __restrict__ W1,
                                                           const float* __restrict__ W2,
                                                           _Float16* __restrict__ wt1,
                                                           _Float16* __restrict__ wt2,
                                                           int E, int chunk, int NB) {
    int t = threadIdx.x;
    if (blockIdx.x >= 256) {
        int idx = (blockIdx.x - 256) * 256 + t;
        if (idx < 128 * 128) {
            int nn = idx >> 7, k = idx & 127;
            wt1[idx] = (_Float16)W1[k * 128 + nn];
        } else if (idx < (128 + 256) * 128) {
            int j = idx - 128 * 128;
            int nn = j >> 7, k = j & 127;
            wt2[j] = (_Float16)W2[k * 256 + nn];
        }
        return;
    }
    extern __shared__ int sh[];       // hist | base_loc | cur2  (3*NB ints)
    int* hist = sh;
    int* base_loc = sh + NB;
    int* cur2 = sh + 2 * NB;
    for (int i = t; i < NB; i += 256) { hist[i] = 0; cur2[i] = 0; }
    __syncthreads();
    int cbeg = blockIdx.x * chunk;
    int cend = min(E, cbeg + chunk);
    for (int e = cbeg + t; e < cend; e += 256)
        atomicAdd(&hist[dst[e] >> BSHIFT], 1);
    __syncthreads();
    for (int i = t; i < NB; i += 256) {
        int c = hist[i];
        base_loc[i] = c ? atomicAdd(&bucket_fill[i], c) : 0;
    }
    __syncthreads();
    for (int e = cbeg + t; e < cend; e += 256) {
        int d = dst[e];
        int bkt = d >> BSHIFT;
        int r = atomicAdd(&cur2[bkt], 1);
        bucketed[(size_t)bkt * BCAP + base_loc[bkt] + r] =
            (unsigned)src[e] | ((unsigned)(d & (BNODES - 1)) << 16);
    }
}

// ---- per-bucket CSR build + dinv + xs conversion ---------------------------
__global__ __launch_bounds__(256) void build_kernel(const unsigned* __restrict__ bucketed,
                                                    const int* __restrict__ bucket_fill,
                                                    const float* __restrict__ x,
                                                    int* __restrict__ rowstart,
                                                    int* __restrict__ rowend,
                                                    float* __restrict__ dinv,
                                                    int* __restrict__ csr,
                                                    _Float16* __restrict__ xs,
                                                    int N, int NB) {
    __shared__ int deg_loc[BNODES];
    __shared__ int tmp[BNODES];
    __shared__ int cur_loc[BNODES];
    __shared__ float dinv_loc[BNODES];
    int t = threadIdx.x;
    int b = blockIdx.x;
    int n0 = b << BSHIFT;
    int nodes_in = min(BNODES, N - n0);
    size_t wbase = (size_t)b * BCAP;
    int cnt = bucket_fill[b];

    if (t < BNODES) deg_loc[t] = 0;
    __syncthreads();
    for (int e = t; e < cnt; e += 256)
        atomicAdd(&deg_loc[bucketed[wbase + e] >> 16], 1);
    __syncthreads();
    if (t < BNODES) tmp[t] = deg_loc[t];
    __syncthreads();
    for (int off = 1; off < BNODES; off <<= 1) {
        int v = 0;
        if (t < BNODES && t >= off) v = tmp[t - off];
        __syncthreads();
        if (t < BNODES) tmp[t] += v;
        __syncthreads();
    }
    if (t < BNODES) {
        int abs0 = (int)wbase + tmp[t] - deg_loc[t];
        cur_loc[t] = abs0;
        float dv = rsqrtf((float)(deg_loc[t] + 1));
        dinv_loc[t] = dv;
        if (t < nodes_in) {
            rowstart[n0 + t] = abs0;
            rowend[n0 + t] = abs0 + deg_loc[t];
            dinv[n0 + t] = dv;
        }
    }
    __syncthreads();
    for (int e = t; e < cnt; e += 256) {
        unsigned u2 = bucketed[wbase + e];
        int pos = atomicAdd(&cur_loc[u2 >> 16], 1);
        csr[pos] = (int)(u2 & 0xFFFFu);
    }
    // xs = fp16(x * dinv) for this bucket's rows (coalesced float4)
    int total4 = nodes_in * 32;  // 32 float4 per 128-wide row
    const float4* x4 = (const float4*)(x + (size_t)n0 * 128);
    for (int i = t; i < total4; i += 256) {
        int row = i >> 5;
        float dv = dinv_loc[row];
        float4 v = x4[i];
        half4v h;
        h[0] = (_Float16)(v.x * dv); h[1] = (_Float16)(v.y * dv);
        h[2] = (_Float16)(v.z * dv); h[3] = (_Float16)(v.w * dv);
        *(half4v*)(xs + (size_t)n0 * 128 + (size_t)i * 4) = h;
    }
}

// ---- column-sliced 128-dim gather aggregation ------------------------------
// q[v] = fp16( dinv[v] * (g[v] + sum_{u->v} g[u]) ), computed in 4 passes of
// 32 halfs (64 B) so each pass's gather slice (3.2 MB) is L2-resident.
// One wave per node per pass; 8 octets x 8 lanes x 8B = one aligned 64B line
// per row per octet -> 8 rows per wave-instruction; x2 unroll -> 16 in flight.
// Pass-major dispatch (pass = blockIdx.x / nb_per_pass) gives temporal
// separation between slices; csr via nontemporal loads (no slice eviction).
__global__ __launch_bounds__(256) void agg128_sliced_kernel(const _Float16* __restrict__ g,
                                                            const int* __restrict__ rowstart,
                                                            const int* __restrict__ rowend,
                                                            const float* __restrict__ dinv,
                                                            const int* __restrict__ csr,
                                                            _Float16* __restrict__ out,
                                                            int n, int nb_per_pass) {
    int pass = blockIdx.x / nb_per_pass;
    int blk  = blockIdx.x - pass * nb_per_pass;
    int wid  = blk * 4 + (threadIdx.x >> 6);   // 4 waves/block, 1 node each
    int lane = threadIdx.x & 63;
    if (wid >= n) return;
    int oct = lane >> 3, l8 = lane & 7;
    const _Float16* gp = g + pass * 32;        // column slice base

    int beg = rowstart[wid], end = rowend[wid];
    float a0 = 0.f, a1 = 0.f, a2 = 0.f, a3 = 0.f;
    if (oct == 0) {  // self term
        half4v s = *(const half4v*)(gp + (size_t)wid * 128 + l8 * 4);
        a0 = (float)s[0]; a1 = (float)s[1]; a2 = (float)s[2]; a3 = (float)s[3];
    }
    int e = beg + oct;
    for (; e + 8 < end; e += 16) {     // 2 rows per octet in flight
        int u0 = __builtin_nontemporal_load(csr + e);
        int u1 = __builtin_nontemporal_load(csr + e + 8);
        half4v v0 = *(const half4v*)(gp + (size_t)u0 * 128 + l8 * 4);
        half4v v1 = *(const half4v*)(gp + (size_t)u1 * 128 + l8 * 4);
        a0 += (float)v0[0] + (float)v1[0];
        a1 += (float)v0[1] + (float)v1[1];
        a2 += (float)v0[2] + (float)v1[2];
        a3 += (float)v0[3] + (float)v1[3];
    }
    for (; e < end; e += 8) {
        int u = __builtin_nontemporal_load(csr + e);
        half4v v = *(const half4v*)(gp + (size_t)u * 128 + l8 * 4);
        a0 += (float)v[0]; a1 += (float)v[1]; a2 += (float)v[2]; a3 += (float)v[3];
    }
    // combine the 8 octet partials
    a0 += __shfl_xor(a0, 8);  a0 += __shfl_xor(a0, 16);  a0 += __shfl_xor(a0, 32);
    a1 += __shfl_xor(a1, 8);  a1 += __shfl_xor(a1, 16);  a1 += __shfl_xor(a1, 32);
    a2 += __shfl_xor(a2, 8);  a2 += __shfl_xor(a2, 16);  a2 += __shfl_xor(a2, 32);
    a3 += __shfl_xor(a3, 8);  a3 += __shfl_xor(a3, 16);  a3 += __shfl_xor(a3, 32);
    if (oct == 0) {
        float dv = dinv[wid];
        half4v o;
        o[0] = (_Float16)(a0 * dv); o[1] = (_Float16)(a1 * dv);
        o[2] = (_Float16)(a2 * dv); o[3] = (_Float16)(a3 * dv);
        *(half4v*)(out + (size_t)pass * 32 + (size_t)wid * 128 + l8 * 4) = o;
    }
}

// ---- fp16 MFMA GEMM, K=128, BM=BN=128, fused epilogue ----------------------
// HALF_OUT: out = fp16(relu(acc+bias)*dinv)   else: fp32 relu(acc+bias)
// MFMA layouts (m89/m120): A[m=lane&15][k=(lane>>4)*8+j], B as Bt[n][k],
// D[row=(lane>>4)*4+reg][col=lane&15].
template <bool HALF_OUT>
__global__ __launch_bounds__(256) void gemm_kernel(const _Float16* __restrict__ A,   // [n][128]
                                                   const _Float16* __restrict__ Bt,  // [nout][128]
                                                   const float* __restrict__ bias,
                                                   const float* __restrict__ dinv,
                                                   void* __restrict__ outp,
                                                   int n, int nout) {
    __shared__ _Float16 As[128][136];
    __shared__ _Float16 Bs[128][136];
    int t = threadIdx.x;
    int row0 = blockIdx.x * 128;
    int col0 = blockIdx.y * 128;

#pragma unroll
    for (int i = 0; i < 8; i++) {
        int c = i * 256 + t;
        int r = c >> 4, seg = c & 15;
        int gr = row0 + r;
        if (gr >= n) gr = n - 1;  // clamp; extra rows never stored
        uint4 v = *(const uint4*)(A + (size_t)gr * 128 + seg * 8);
        *(uint4*)(&As[r][seg * 8]) = v;
    }
#pragma unroll
    for (int i = 0; i < 8; i++) {
        int c = i * 256 + t;
        int r = c >> 4, seg = c & 15;
        uint4 v = *(const uint4*)(Bt + (size_t)(col0 + r) * 128 + seg * 8);
        *(uint4*)(&Bs[r][seg * 8]) = v;
    }
    __syncthreads();

    int wid = t >> 6, lane = t & 63;
    int wm = wid >> 1, wn = wid & 1;
    int quad = lane >> 4, l16 = lane & 15;

    floatx4 acc[4][4];
#pragma unroll
    for (int mt = 0; mt < 4; mt++)
#pragma unroll
        for (int nt = 0; nt < 4; nt++) acc[mt][nt] = (floatx4){0.f, 0.f, 0.f, 0.f};

#pragma unroll
    for (int ks = 0; ks < 4; ks++) {
        int k0 = ks * 32 + quad * 8;
        half8 a[4], b[4];
#pragma unroll
        for (int mt = 0; mt < 4; mt++)
            a[mt] = *(const half8*)(&As[wm * 64 + mt * 16 + l16][k0]);
#pragma unroll
        for (int nt = 0; nt < 4; nt++)
            b[nt] = *(const half8*)(&Bs[wn * 64 + nt * 16 + l16][k0]);
#pragma unroll
        for (int mt = 0; mt < 4; mt++)
#pragma unroll
            for (int nt = 0; nt < 4; nt++)
                acc[mt][nt] = __builtin_amdgcn_mfma_f32_16x16x32_f16(a[mt], b[nt], acc[mt][nt], 0, 0, 0);
    }

#pragma unroll
    for (int mt = 0; mt < 4; mt++) {
        int rbase = row0 + wm * 64 + mt * 16 + quad * 4;
#pragma unroll
        for (int reg = 0; reg < 4; reg++) {
            int r = rbase + reg;
            if (r < n) {
                float dv = HALF_OUT ? dinv[r] : 1.f;
#pragma unroll
                for (int nt = 0; nt < 4; nt++) {
                    int cc = col0 + wn * 64 + nt * 16 + l16;
                    float val = fmaxf(acc[mt][nt][reg] + bias[cc], 0.f);
                    if (HALF_OUT)
                        ((_Float16*)outp)[(size_t)r * nout + cc] = (_Float16)(val * dv);
                    else
                        ((float*)outp)[(size_t)r * nout + cc] = val;
                }
            }
        }
    }
}

extern "C" void kernel_launch(void* const* d_in, const int* in_sizes, int n_in,
                              void* d_out, int out_size, void* d_ws, size_t ws_size,
                              hipStream_t stream) {
    const float* x  = (const float*)d_in[0];
    const int*   ei = (const int*)d_in[1];
    const float* W1 = (const float*)d_in[2];
    const float* b1 = (const float*)d_in[3];
    const float* W2 = (const float*)d_in[4];
    const float* b2 = (const float*)d_in[5];
    float* out = (float*)d_out;

    int N = in_sizes[0] / 128;   // 50000
    int E = in_sizes[1] / 2;     // 800000
    const int* src = ei;
    const int* dst = ei + E;
    int NB = (N + BNODES - 1) >> BSHIFT;   // 391 buckets

    char* w = (char*)d_ws;
    size_t off = 0;
    auto alloc = [&](size_t bytes) -> char* {
        char* p = w + off;
        off = (off + bytes + 255) & ~(size_t)255;
        return p;
    };
    int*      bucket_fill = (int*)alloc((size_t)NB * 4);
    unsigned* bucketed    = (unsigned*)alloc((size_t)NB * BCAP * 4);
    int*      rowstart    = (int*)alloc((size_t)N * 4);
    int*      rowend      = (int*)alloc((size_t)N * 4);
    float*    dinv        = (float*)alloc((size_t)N * 4);
    int*      csr         = (int*)alloc((size_t)NB * BCAP * 4);
    _Float16* wt1         = (_Float16*)alloc((size_t)128 * 128 * 2);
    _Float16* wt2         = (_Float16*)alloc((size_t)256 * 128 * 2);
    _Float16* xs          = (_Float16*)alloc((size_t)N * 128 * 2);
    _Float16* q1          = (_Float16*)alloc((size_t)N * 128 * 2);
    _Float16* p2          = (_Float16*)alloc((size_t)N * 128 * 2);
    _Float16* q2          = (_Float16*)alloc((size_t)N * 128 * 2);

    int chunk = (E + 255) / 256;          // edges per scatter block
    size_t lds3 = (size_t)NB * 12;        // scatter hist+base+cur

    hipMemsetAsync(bucket_fill, 0, (size_t)NB * 4, stream);
    hipLaunchKernelGGL(scatter_conv_kernel, dim3(256 + 192), dim3(256), lds3, stream,
                       src, dst, bucket_fill, bucketed, W1, W2, wt1, wt2, E, chunk, NB);
    hipLaunchKernelGGL(build_kernel, dim3(NB), dim3(256), 0, stream,
                       bucketed, bucket_fill, x, rowstart, rowend, dinv, csr, xs, N, NB);

    int gbm = (N + 127) / 128;      // 391
    int nb_per_pass = (N + 3) / 4;  // 12500
    int nb_agg = nb_per_pass * 4;   // 4 column-slice passes, pass-major
    // layer 1
    hipLaunchKernelGGL(agg128_sliced_kernel, dim3(nb_agg), dim3(256), 0, stream,
                       xs, rowstart, rowend, dinv, csr, q1, N, nb_per_pass);
    hipLaunchKernelGGL((gemm_kernel<true>), dim3(gbm, 1), dim3(256), 0, stream, q1, wt1, b1, dinv, (void*)p2, N, 128);
    // layer 2
    hipLaunchKernelGGL(agg128_sliced_kernel, dim3(nb_agg), dim3(256), 0, stream,
                       p2, rowstart, rowend, dinv, csr, q2, N, nb_per_pass);
    hipLaunchKernelGGL((gemm_kernel<false>), dim3(gbm, 2), dim3(256), 0, stream, q2, wt2, b2, dinv, (void*)out, N, 256);
}

// Round 9
// 213.820 us; speedup vs baseline: 1.4937x; 1.4937x over previous
//
#include <hip/hip_runtime.h>

// ---------------------------------------------------------------------------
// 2-layer GCN, R9 = R7 verbatim (measured best, 214.1 us).
// R6 (fuse gather into GEMM blocks) regressed: gather needs ~12k independent
// blocks of TLP; 391 blocks -> 15% occupancy -> gather BW halved.
// R8 (column-sliced gather for L2 residency) regressed: no temporal control
// over block scheduling -> slices interleave, strided access leaks to HBM
// (FETCH 126 MB/agg). Full-row gather + LLC residency is the right shape.
// Structure:
//   scatter: packed (src|dst_low7<<16) into fixed per-bucket windows
//            (Binomial(800k,1/391) ~ 2046+-45 << CAP 4096), W fp16-transpose
//            rides on spare blocks.
//   build:   per-bucket LDS degree/scan/fill -> rowstart/rowend/dinv/csr,
//            xs = fp16(x*dinv) fused.
//   q1 = fp16(dinv*(xs_self + sum xs[u]))   [agg128: quarter-wave rows, x4 ILP]
//   p2 = fp16(relu(q1@W1+b1)*dinv)          [MFMA gemm, fused epilogue]
//   q2 = fp16(dinv*(p2_self + sum p2[u]))   [agg128]
//   out = relu(q2@W2+b2) fp32               [MFMA gemm]
// ---------------------------------------------------------------------------

typedef __attribute__((ext_vector_type(8))) _Float16 half8;
typedef __attribute__((ext_vector_type(4))) _Float16 half4v;
typedef __attribute__((ext_vector_type(4))) float floatx4;

#define BSHIFT 7
#define BNODES 128       // nodes per bucket
#define BCAP   4096      // edge capacity per bucket (mean 2046, sigma ~45)

// ---- scatter packed (src | dst_low7<<16) into fixed bucket windows ---------
// Blocks [0,256): scatter. Blocks [256,448): W1/W2 fp32 -> fp16 transposed.
__global__ __launch_bounds__(256) void scatter_conv_kernel(const int* __restrict__ src,
                                                           const int* __restrict__ dst,
                                                           int* __restrict__ bucket_fill,
                                                           unsigned* __restrict__ bucketed,
                                                           const float* __restrict__ W1,
                                                           const float* __restrict__ W2,
                                                           _Float16* __restrict__ wt1,
                                                           _Float16* __restrict__ wt2,
                                                           int E, int chunk, int NB) {
    int t = threadIdx.x;
    if (blockIdx.x >= 256) {
        int idx = (blockIdx.x - 256) * 256 + t;
        if (idx < 128 * 128) {
            int nn = idx >> 7, k = idx & 127;
            wt1[idx] = (_Float16)W1[k * 128 + nn];
        } else if (idx < (128 + 256) * 128) {
            int j = idx - 128 * 128;
            int nn = j >> 7, k = j & 127;
            wt2[j] = (_Float16)W2[k * 256 + nn];
        }
        return;
    }
    extern __shared__ int sh[];       // hist | base_loc | cur2  (3*NB ints)
    int* hist = sh;
    int* base_loc = sh + NB;
    int* cur2 = sh + 2 * NB;
    for (int i = t; i < NB; i += 256) { hist[i] = 0; cur2[i] = 0; }
    __syncthreads();
    int cbeg = blockIdx.x * chunk;
    int cend = min(E, cbeg + chunk);
    for (int e = cbeg + t; e < cend; e += 256)
        atomicAdd(&hist[dst[e] >> BSHIFT], 1);
    __syncthreads();
    for (int i = t; i < NB; i += 256) {
        int c = hist[i];
        base_loc[i] = c ? atomicAdd(&bucket_fill[i], c) : 0;
    }
    __syncthreads();
    for (int e = cbeg + t; e < cend; e += 256) {
        int d = dst[e];
        int bkt = d >> BSHIFT;
        int r = atomicAdd(&cur2[bkt], 1);
        bucketed[(size_t)bkt * BCAP + base_loc[bkt] + r] =
            (unsigned)src[e] | ((unsigned)(d & (BNODES - 1)) << 16);
    }
}

// ---- per-bucket CSR build + dinv + xs conversion ---------------------------
__global__ __launch_bounds__(256) void build_kernel(const unsigned* __restrict__ bucketed,
                                                    const int* __restrict__ bucket_fill,
                                                    const float* __restrict__ x,
                                                    int* __restrict__ rowstart,
                                                    int* __restrict__ rowend,
                                                    float* __restrict__ dinv,
                                                    int* __restrict__ csr,
                                                    _Float16* __restrict__ xs,
                                                    int N, int NB) {
    __shared__ int deg_loc[BNODES];
    __shared__ int tmp[BNODES];
    __shared__ int cur_loc[BNODES];
    __shared__ float dinv_loc[BNODES];
    int t = threadIdx.x;
    int b = blockIdx.x;
    int n0 = b << BSHIFT;
    int nodes_in = min(BNODES, N - n0);
    size_t wbase = (size_t)b * BCAP;
    int cnt = bucket_fill[b];

    if (t < BNODES) deg_loc[t] = 0;
    __syncthreads();
    for (int e = t; e < cnt; e += 256)
        atomicAdd(&deg_loc[bucketed[wbase + e] >> 16], 1);
    __syncthreads();
    if (t < BNODES) tmp[t] = deg_loc[t];
    __syncthreads();
    for (int off = 1; off < BNODES; off <<= 1) {
        int v = 0;
        if (t < BNODES && t >= off) v = tmp[t - off];
        __syncthreads();
        if (t < BNODES) tmp[t] += v;
        __syncthreads();
    }
    if (t < BNODES) {
        int abs0 = (int)wbase + tmp[t] - deg_loc[t];
        cur_loc[t] = abs0;
        float dv = rsqrtf((float)(deg_loc[t] + 1));
        dinv_loc[t] = dv;
        if (t < nodes_in) {
            rowstart[n0 + t] = abs0;
            rowend[n0 + t] = abs0 + deg_loc[t];
            dinv[n0 + t] = dv;
        }
    }
    __syncthreads();
    for (int e = t; e < cnt; e += 256) {
        unsigned u2 = bucketed[wbase + e];
        int pos = atomicAdd(&cur_loc[u2 >> 16], 1);
        csr[pos] = (int)(u2 & 0xFFFFu);
    }
    // xs = fp16(x * dinv) for this bucket's rows (coalesced float4)
    int total4 = nodes_in * 32;  // 32 float4 per 128-wide row
    const float4* x4 = (const float4*)(x + (size_t)n0 * 128);
    for (int i = t; i < total4; i += 256) {
        int row = i >> 5;
        float dv = dinv_loc[row];
        float4 v = x4[i];
        half4v h;
        h[0] = (_Float16)(v.x * dv); h[1] = (_Float16)(v.y * dv);
        h[2] = (_Float16)(v.z * dv); h[3] = (_Float16)(v.w * dv);
        *(half4v*)(xs + (size_t)n0 * 128 + (size_t)i * 4) = h;
    }
}

// ---- 128-dim gather aggregation, quarter-wave rows, 4x unroll --------------
// q[v] = fp16( dinv[v] * (g[v] + sum_{u->v} g[u]) ); g rows = 256B fp16.
// 16 lanes x 16B per row -> 4 rows/wave-instruction; x4 unroll -> 16 in flight.
__global__ __launch_bounds__(256) void agg128_kernel(const _Float16* __restrict__ g,
                                                     const int* __restrict__ rowstart,
                                                     const int* __restrict__ rowend,
                                                     const float* __restrict__ dinv,
                                                     const int* __restrict__ csr,
                                                     _Float16* __restrict__ out, int n) {
    int wid = (blockIdx.x * blockDim.x + threadIdx.x) >> 6;
    int lane = threadIdx.x & 63;
    if (wid >= n) return;
    int q = lane >> 4, l16 = lane & 15;
    int beg = rowstart[wid], end = rowend[wid];

    float a[8] = {0.f, 0.f, 0.f, 0.f, 0.f, 0.f, 0.f, 0.f};
    if (q == 0) {  // self term
        half8 v = *(const half8*)(g + (size_t)wid * 128 + l16 * 8);
#pragma unroll
        for (int j = 0; j < 8; j++) a[j] = (float)v[j];
    }
    int e = beg + q;
    for (; e + 12 < end; e += 16) {   // 4 rows per quarter in flight
        int u0 = csr[e];
        int u1 = csr[e + 4];
        int u2 = csr[e + 8];
        int u3 = csr[e + 12];
        half8 v0 = *(const half8*)(g + (size_t)u0 * 128 + l16 * 8);
        half8 v1 = *(const half8*)(g + (size_t)u1 * 128 + l16 * 8);
        half8 v2 = *(const half8*)(g + (size_t)u2 * 128 + l16 * 8);
        half8 v3 = *(const half8*)(g + (size_t)u3 * 128 + l16 * 8);
#pragma unroll
        for (int j = 0; j < 8; j++)
            a[j] += ((float)v0[j] + (float)v1[j]) + ((float)v2[j] + (float)v3[j]);
    }
    for (; e + 4 < end; e += 8) {     // 2 rows in flight
        int u0 = csr[e];
        int u1 = csr[e + 4];
        half8 v0 = *(const half8*)(g + (size_t)u0 * 128 + l16 * 8);
        half8 v1 = *(const half8*)(g + (size_t)u1 * 128 + l16 * 8);
#pragma unroll
        for (int j = 0; j < 8; j++) a[j] += (float)v0[j] + (float)v1[j];
    }
    for (; e < end; e += 4) {
        int u = csr[e];
        half8 v = *(const half8*)(g + (size_t)u * 128 + l16 * 8);
#pragma unroll
        for (int j = 0; j < 8; j++) a[j] += (float)v[j];
    }
#pragma unroll
    for (int j = 0; j < 8; j++) {
        a[j] += __shfl_xor(a[j], 16);
        a[j] += __shfl_xor(a[j], 32);
    }
    if (q == 0) {
        float dv = dinv[wid];
        half8 o;
#pragma unroll
        for (int j = 0; j < 8; j++) o[j] = (_Float16)(a[j] * dv);
        *(half8*)(out + (size_t)wid * 128 + l16 * 8) = o;
    }
}

// ---- fp16 MFMA GEMM, K=128, BM=BN=128, fused epilogue ----------------------
// HALF_OUT: out = fp16(relu(acc+bias)*dinv)   else: fp32 relu(acc+bias)
// MFMA layouts (m89/m120): A[m=lane&15][k=(lane>>4)*8+j], B as Bt[n][k],
// D[row=(lane>>4)*4+reg][col=lane&15].
template <bool HALF_OUT>
__global__ __launch_bounds__(256) void gemm_kernel(const _Float16* __restrict__ A,   // [n][128]
                                                   const _Float16* __restrict__ Bt,  // [nout][128]
                                                   const float* __restrict__ bias,
                                                   const float* __restrict__ dinv,
                                                   void* __restrict__ outp,
                                                   int n, int nout) {
    __shared__ _Float16 As[128][136];
    __shared__ _Float16 Bs[128][136];
    int t = threadIdx.x;
    int row0 = blockIdx.x * 128;
    int col0 = blockIdx.y * 128;

#pragma unroll
    for (int i = 0; i < 8; i++) {
        int c = i * 256 + t;
        int r = c >> 4, seg = c & 15;
        int gr = row0 + r;
        if (gr >= n) gr = n - 1;  // clamp; extra rows never stored
        uint4 v = *(const uint4*)(A + (size_t)gr * 128 + seg * 8);
        *(uint4*)(&As[r][seg * 8]) = v;
    }
#pragma unroll
    for (int i = 0; i < 8; i++) {
        int c = i * 256 + t;
        int r = c >> 4, seg = c & 15;
        uint4 v = *(const uint4*)(Bt + (size_t)(col0 + r) * 128 + seg * 8);
        *(uint4*)(&Bs[r][seg * 8]) = v;
    }
    __syncthreads();

    int wid = t >> 6, lane = t & 63;
    int wm = wid >> 1, wn = wid & 1;
    int quad = lane >> 4, l16 = lane & 15;

    floatx4 acc[4][4];
#pragma unroll
    for (int mt = 0; mt < 4; mt++)
#pragma unroll
        for (int nt = 0; nt < 4; nt++) acc[mt][nt] = (floatx4){0.f, 0.f, 0.f, 0.f};

#pragma unroll
    for (int ks = 0; ks < 4; ks++) {
        int k0 = ks * 32 + quad * 8;
        half8 a[4], b[4];
#pragma unroll
        for (int mt = 0; mt < 4; mt++)
            a[mt] = *(const half8*)(&As[wm * 64 + mt * 16 + l16][k0]);
#pragma unroll
        for (int nt = 0; nt < 4; nt++)
            b[nt] = *(const half8*)(&Bs[wn * 64 + nt * 16 + l16][k0]);
#pragma unroll
        for (int mt = 0; mt < 4; mt++)
#pragma unroll
            for (int nt = 0; nt < 4; nt++)
                acc[mt][nt] = __builtin_amdgcn_mfma_f32_16x16x32_f16(a[mt], b[nt], acc[mt][nt], 0, 0, 0);
    }

#pragma unroll
    for (int mt = 0; mt < 4; mt++) {
        int rbase = row0 + wm * 64 + mt * 16 + quad * 4;
#pragma unroll
        for (int reg = 0; reg < 4; reg++) {
            int r = rbase + reg;
            if (r < n) {
                float dv = HALF_OUT ? dinv[r] : 1.f;
#pragma unroll
                for (int nt = 0; nt < 4; nt++) {
                    int cc = col0 + wn * 64 + nt * 16 + l16;
                    float val = fmaxf(acc[mt][nt][reg] + bias[cc], 0.f);
                    if (HALF_OUT)
                        ((_Float16*)outp)[(size_t)r * nout + cc] = (_Float16)(val * dv);
                    else
                        ((float*)outp)[(size_t)r * nout + cc] = val;
                }
            }
        }
    }
}

extern "C" void kernel_launch(void* const* d_in, const int* in_sizes, int n_in,
                              void* d_out, int out_size, void* d_ws, size_t ws_size,
                              hipStream_t stream) {
    const float* x  = (const float*)d_in[0];
    const int*   ei = (const int*)d_in[1];
    const float* W1 = (const float*)d_in[2];
    const float* b1 = (const float*)d_in[3];
    const float* W2 = (const float*)d_in[4];
    const float* b2 = (const float*)d_in[5];
    float* out = (float*)d_out;

    int N = in_sizes[0] / 128;   // 50000
    int E = in_sizes[1] / 2;     // 800000
    const int* src = ei;
    const int* dst = ei + E;
    int NB = (N + BNODES - 1) >> BSHIFT;   // 391 buckets

    char* w = (char*)d_ws;
    size_t off = 0;
    auto alloc = [&](size_t bytes) -> char* {
        char* p = w + off;
        off = (off + bytes + 255) & ~(size_t)255;
        return p;
    };
    int*      bucket_fill = (int*)alloc((size_t)NB * 4);
    unsigned* bucketed    = (unsigned*)alloc((size_t)NB * BCAP * 4);
    int*      rowstart    = (int*)alloc((size_t)N * 4);
    int*      rowend      = (int*)alloc((size_t)N * 4);
    float*    dinv        = (float*)alloc((size_t)N * 4);
    int*      csr         = (int*)alloc((size_t)NB * BCAP * 4);
    _Float16* wt1         = (_Float16*)alloc((size_t)128 * 128 * 2);
    _Float16* wt2         = (_Float16*)alloc((size_t)256 * 128 * 2);
    _Float16* xs          = (_Float16*)alloc((size_t)N * 128 * 2);
    _Float16* q1          = (_Float16*)alloc((size_t)N * 128 * 2);
    _Float16* p2          = (_Float16*)alloc((size_t)N * 128 * 2);
    _Float16* q2          = (_Float16*)alloc((size_t)N * 128 * 2);

    int chunk = (E + 255) / 256;          // edges per scatter block
    size_t lds3 = (size_t)NB * 12;        // scatter hist+base+cur

    hipMemsetAsync(bucket_fill, 0, (size_t)NB * 4, stream);
    hipLaunchKernelGGL(scatter_conv_kernel, dim3(256 + 192), dim3(256), lds3, stream,
                       src, dst, bucket_fill, bucketed, W1, W2, wt1, wt2, E, chunk, NB);
    hipLaunchKernelGGL(build_kernel, dim3(NB), dim3(256), 0, stream,
                       bucketed, bucket_fill, x, rowstart, rowend, dinv, csr, xs, N, NB);

    int gbm = (N + 127) / 128;   // 391
    int nb_agg = (N + 3) / 4;
    // layer 1
    hipLaunchKernelGGL(agg128_kernel, dim3(nb_agg), dim3(256), 0, stream, xs, rowstart, rowend, dinv, csr, q1, N);
    hipLaunchKernelGGL((gemm_kernel<true>), dim3(gbm, 1), dim3(256), 0, stream, q1, wt1, b1, dinv, (void*)p2, N, 128);
    // layer 2
    hipLaunchKernelGGL(agg128_kernel, dim3(nb_agg), dim3(256), 0, stream, p2, rowstart, rowend, dinv, csr, q2, N);
    hipLaunchKernelGGL((gemm_kernel<false>), dim3(gbm, 2), dim3(256), 0, stream, q2, wt2, b2, dinv, (void*)out, N, 256);
}